// Round 6
// baseline (2262.820 us; speedup 1.0000x reference)
//
#include <hip/hip_runtime.h>
#include <math.h>

#ifndef M_PI
#define M_PI 3.14159265358979323846
#endif

constexpr int S_LEN    = 176400;
constexpr int NFFT     = 2048;
constexpr int NC       = 1024;
constexpr int HOP_     = 441;
constexpr int T_FRAMES = 401;
constexpr int F_BINS   = 1025;
constexpr int F_STRIDE = 1028;     // fp32 spec row stride (16B aligned)
constexpr int N_CH     = 64;
constexpr float EPS_   = 1e-8f;
constexpr float C1_    = 0.0004f;
constexpr float C2_    = 0.0036f;
constexpr float COV_NORM_ = 49.0f / 48.0f;

// workspace float offsets
constexpr int WIN_OFF  = 0;        // float[2048] hann window
constexpr int TWG_OFF  = 2048;     // float2[768]  tw[e] = exp(-2pi i e/1024)
constexpr int UTW_OFF  = 3584;     // float2[1025] exp(-i pi r/1024)
constexpr int CNT_OFF  = 5636;     // int[68]: [0]=stft queue, [1..64]=done, [65]=ssim queue
constexpr int SPEC_OFF = 5704;     // 16B aligned

// fused-kernel ticket layout
constexpr int NTICK_STFT = N_CH * T_FRAMES;          // 25664, ticket = ch*401 + t
constexpr int SSIM_BANDS = 9;                        // 2 cols/lane, 61 producing lanes
constexpr int SSIM_CHUNK = 25;                       // 16-row chunks over 395 rows
constexpr int SSIM_WPC   = SSIM_BANDS * SSIM_CHUNK;  // 225 waves per channel
constexpr int NWAVE_SSIM = N_CH * SSIM_WPC;          // 14400
constexpr int NTICK_SSIM = NWAVE_SSIM / 4;           // 3600 block tickets
constexpr int PERSIST_BLOCKS = 2048;                 // 8 blocks/CU x 256 CUs

// legacy-fallback ssim decomposition (R5)
constexpr int ROWS_PW   = 24;
constexpr int NCHUNKS_R = 17;
constexpr int BANDS     = 5;
constexpr int BAND_ADV  = 248;

// LDS bank swizzle: phys(i) = i ^ ((i>>2)&15) ^ ((i>>6)&15) (bijective, conflict-checked)
__device__ __forceinline__ int phys(int i) { return i ^ ((i >> 2) & 15) ^ ((i >> 6) & 15); }

__device__ __forceinline__ float2 cadd(float2 a, float2 b){ return make_float2(a.x+b.x, a.y+b.y); }
__device__ __forceinline__ float2 csub(float2 a, float2 b){ return make_float2(a.x-b.x, a.y-b.y); }
__device__ __forceinline__ float2 cmul(float2 a, float2 b){ return make_float2(a.x*b.x-a.y*b.y, a.x*b.y+a.y*b.x); }

// agent-scope (coherence-point) 8B load: immune to stale per-XCD L2 lines
__device__ __forceinline__ float2 sld2(const float* p) {
    unsigned long long v = __hip_atomic_load((const unsigned long long*)p,
                                             __ATOMIC_RELAXED, __HIP_MEMORY_SCOPE_AGENT);
    float2 f;
    f.x = __uint_as_float((unsigned)(v & 0xffffffffull));
    f.y = __uint_as_float((unsigned)(v >> 32));
    return f;
}

__global__ __launch_bounds__(256) void init_tables_kernel(float* __restrict__ ws, float* __restrict__ out) {
    const int idx = blockIdx.x * 256 + threadIdx.x;
    if (idx < 64) out[idx] = 0.0f;
    if (idx < 68) ((int*)(ws + CNT_OFF))[idx] = 0;
    if (idx < NFFT) {
        ws[WIN_OFF + idx] = 0.5f - 0.5f * cosf((float)(2.0 * M_PI / NFFT) * (float)idx);
    }
    if (idx < 768) {
        float ang = -2.0f * (float)M_PI * (float)idx / (float)NC;
        float s, c; sincosf(ang, &s, &c);
        ws[TWG_OFF + 2*idx] = c; ws[TWG_OFF + 2*idx+1] = s;
    }
    if (idx < F_BINS) {
        float ang = -(float)M_PI * (float)idx / (float)NC;
        float s, c; sincosf(ang, &s, &c);
        ws[UTW_OFF + 2*idx] = c; ws[UTW_OFF + 2*idx+1] = s;
    }
}

// In-place radix-4 DIF butterfly (R2-verified)
__device__ __forceinline__ void r4_dif_inplace(
    float2* __restrict__ A, int r0, int r1, int r2, int r3,
    float2 w1, float2 w2, float2 w3, bool tw)
{
    float2 x0c = A[r0];
    float2 x1c = A[r1];
    float2 x2c = A[r2];
    float2 x3c = A[r3];

    float2 a = cadd(x0c, x2c);
    float2 b = csub(x0c, x2c);
    float2 c = cadd(x1c, x3c);
    float2 d = csub(x1c, x3c);

    float2 y0 = cadd(a, c);
    float2 y2 = csub(a, c);
    float2 y1 = make_float2(b.x + d.y, b.y - d.x);   // b - i*d
    float2 y3 = make_float2(b.x - d.y, b.y + d.x);   // b + i*d

    A[r0] = y0;
    A[r1] = tw ? cmul(y1, w1) : y1;
    A[r2] = tw ? cmul(y2, w2) : y2;
    A[r3] = tw ? cmul(y3, w3) : y3;
}

// Dual 1024-pt in-place radix-4 DIF for one (frame, channel): both tensors.
// ATOMIC_ST: spec stores as agent-scope atomics (fused producer/consumer path).
template<bool ATOMIC_ST>
__device__ __forceinline__ void stft_pair_body(
    const float* __restrict__ xin0, const float* __restrict__ xin1,
    const float* __restrict__ ws, float2* __restrict__ buf,
    int t, float* __restrict__ sout0, float* __restrict__ sout1, int tid)
{
    const float*  __restrict__ win = ws + WIN_OFF;
    const float2* __restrict__ twg = (const float2*)(ws + TWG_OFF);
    const float2* __restrict__ utw = (const float2*)(ws + UTW_OFF);

    // ---- pack
    const int base = t * HOP_ - NFFT / 2;
    float* fA0 = (float*)buf;
    float* fA1 = (float*)(buf + NC);
    if (base >= 0 && base + NFFT <= S_LEN) {
        #pragma unroll
        for (int k = 0; k < NFFT / 256; ++k) {
            int n = k * 256 + tid;
            int j = base + n;
            float w = win[n];
            int p = 2 * phys(n >> 1) + (n & 1);
            fA0[p] = xin0[j] * w;
            fA1[p] = xin1[j] * w;
        }
    } else {
        #pragma unroll
        for (int k = 0; k < NFFT / 256; ++k) {
            int n = k * 256 + tid;
            int j = base + n;
            j = (j < 0) ? -j : j;
            j = (j >= S_LEN) ? (2 * S_LEN - 2 - j) : j;
            float w = win[n];
            int p = 2 * phys(n >> 1) + (n & 1);
            fA0[p] = xin0[j] * w;
            fA1[p] = xin1[j] * w;
        }
    }
    __syncthreads();

    // ---- 5 stages, x2 FFTs
    #pragma unroll
    for (int s = 0; s < 5; ++s) {
        const int M  = 256 >> (2 * s);
        const int q  = tid & (M - 1);
        const int e  = q << (2 * s);
        const int i0 = 4 * (tid - q) + q;

        const int r0 = phys(i0);
        const int r1 = phys(i0 + M);
        const int r2 = phys(i0 + 2 * M);
        const int r3 = phys(i0 + 3 * M);

        float2 w1, w2, w3;
        if (s < 4) {
            w1 = twg[e];
            w2 = twg[2 * e];
            w3 = twg[3 * e];
        } else {
            w1 = w2 = w3 = make_float2(1.0f, 0.0f);
        }

        r4_dif_inplace(buf,      r0, r1, r2, r3, w1, w2, w3, s < 4);
        r4_dif_inplace(buf + NC, r0, r1, r2, r3, w1, w2, w3, s < 4);

        __syncthreads();
    }

    // ---- unpack + magnitude + stores
    const int R8 = ((tid & 3) << 6) | ((tid & 12) << 2) | ((tid >> 2) & 12) | ((tid >> 6) & 3);

    #pragma unroll
    for (int k = 0; k < 5; ++k) {
        int r = k * 256 + tid;
        if (k < 4 || tid == 0) {
            const int ra = (k < 4) ? ((R8 << 2) | k) : 0;
            const int rn = (NC - r) & (NC - 1);
            const int rb = ((rn & 3) << 8) | ((rn & 12) << 4) | (rn & 48)
                         | ((rn >> 4) & 12) | ((rn >> 8) & 3);
            const int ia = phys(ra);
            const int ib = phys(rb);
            float2 wu = utw[r];

            {
                float2 Zr = buf[ia];
                float2 Zn = buf[ib];
                float Ex = 0.5f * (Zr.x + Zn.x);
                float Ey = 0.5f * (Zr.y - Zn.y);
                float Ox = 0.5f * (Zr.y + Zn.y);
                float Oy = 0.5f * (Zn.x - Zr.x);
                float Xx = Ex + wu.x * Ox - wu.y * Oy;
                float Xy = Ey + wu.x * Oy + wu.y * Ox;
                float v = sqrtf(fmaxf(Xx * Xx + Xy * Xy, EPS_));
                if constexpr (ATOMIC_ST)
                    __hip_atomic_store(&sout0[r], v, __ATOMIC_RELAXED, __HIP_MEMORY_SCOPE_AGENT);
                else
                    sout0[r] = v;
            }
            {
                float2 Zr = buf[NC + ia];
                float2 Zn = buf[NC + ib];
                float Ex = 0.5f * (Zr.x + Zn.x);
                float Ey = 0.5f * (Zr.y - Zn.y);
                float Ox = 0.5f * (Zr.y + Zn.y);
                float Oy = 0.5f * (Zn.x - Zr.x);
                float Xx = Ex + wu.x * Ox - wu.y * Oy;
                float Xy = Ey + wu.x * Oy + wu.y * Ox;
                float v = sqrtf(fmaxf(Xx * Xx + Xy * Xy, EPS_));
                if constexpr (ATOMIC_ST)
                    __hip_atomic_store(&sout1[r], v, __ATOMIC_RELAXED, __HIP_MEMORY_SCOPE_AGENT);
                else
                    sout1[r] = v;
            }
        }
    }
}

// ---------- fused-path ssim: one wave = (channel, 122-col band, 16-row chunk),
// 2 cols/lane (low VGPR so stft keeps 8 blocks/CU).  Horizontal 7-window from
// per-lane 2-col prefixes + __shfl_down(1,2,3).  Reads via agent-scope loads.
#define HWIN2(s0, s1, W0, W1) {                                              \
    float P  = (s0) + (s1);                                                  \
    float P1 = __shfl_down(P, 1, 64);                                        \
    float P2 = __shfl_down(P, 2, 64);                                        \
    float P3 = __shfl_down(P, 3, 64);                                        \
    float q3 = __shfl_down((s0), 3, 64);                                     \
    float Q  = P1 + P2;                                                      \
    W0 = P + Q + q3;                                                         \
    W1 = P - (s0) + Q + P3;                                                  \
}

__device__ void ssim_wave(const float* __restrict__ ws, float* __restrict__ out,
                          int* __restrict__ cnt, int wid, int lane)
{
    const int cg    = wid / SSIM_WPC;
    const int rem   = wid - cg * SSIM_WPC;
    const int band  = rem / SSIM_CHUNK;
    const int chunk = rem - band * SSIM_CHUNK;

    const int t0 = 3 + chunk * 16;
    const int t1 = min(t0 + 16, T_FRAMES - 3);   // <= 398
    const int cb = band * 122;
    int c2 = cb + 2 * lane;
    if (c2 > 1026) c2 = 1026;                    // in-row clamp; garbage guarded below

    const size_t perT = (size_t)T_FRAMES * F_STRIDE;
    const float* __restrict__ X = ws + SPEC_OFF + (size_t)cg * perT + c2;
    const float* __restrict__ Y = ws + SPEC_OFF + (size_t)(N_CH + cg) * perT + c2;

    const int  fo = cb + 3 + 2 * lane;           // first output col
    const bool ok = (lane <= 60);
    const float inv49 = 1.0f / 49.0f;

    // wait for full channel production (relaxed agent poll -> no cache thrash)
    while (__hip_atomic_load(&cnt[1 + cg], __ATOMIC_RELAXED, __HIP_MEMORY_SCOPE_AGENT) < T_FRAMES)
        __builtin_amdgcn_s_sleep(8);

    float sx0=0,sx1=0, sy0=0,sy1=0, sxx0=0,sxx1=0, syy0=0,syy1=0, sxy0=0,sxy1=0;

    for (int rr = t0 - 3; rr < t0 + 3; ++rr) {
        float2 xv = sld2(X + (size_t)rr * F_STRIDE);
        float2 yv = sld2(Y + (size_t)rr * F_STRIDE);
        sx0 += xv.x; sx1 += xv.y; sy0 += yv.x; sy1 += yv.y;
        sxx0 += xv.x*xv.x; sxx1 += xv.y*xv.y;
        syy0 += yv.x*yv.x; syy1 += yv.y*yv.y;
        sxy0 += xv.x*yv.x; sxy1 += xv.y*yv.y;
    }

    double acc = 0.0;

    #pragma unroll 1
    for (int t = t0; t < t1; ++t) {
        {   // add row t+3
            float2 xv = sld2(X + (size_t)(t + 3) * F_STRIDE);
            float2 yv = sld2(Y + (size_t)(t + 3) * F_STRIDE);
            sx0 += xv.x; sx1 += xv.y; sy0 += yv.x; sy1 += yv.y;
            sxx0 += xv.x*xv.x; sxx1 += xv.y*xv.y;
            syy0 += yv.x*yv.x; syy1 += yv.y*yv.y;
            sxy0 += xv.x*yv.x; sxy1 += xv.y*yv.y;
        }

        float wx0,wx1, wy0,wy1, wxx0,wxx1, wyy0,wyy1, wxy0,wxy1;
        HWIN2(sx0,  sx1,  wx0,  wx1);
        HWIN2(sy0,  sy1,  wy0,  wy1);
        HWIN2(sxx0, sxx1, wxx0, wxx1);
        HWIN2(syy0, syy1, wyy0, wyy1);
        HWIN2(sxy0, sxy1, wxy0, wxy1);

        if (ok && fo <= 1021) {
            float ux  = wx0 * inv49, uy  = wy0 * inv49;
            float uxx = wxx0 * inv49, uyy = wyy0 * inv49, uxy = wxy0 * inv49;
            float vx  = COV_NORM_ * (uxx - ux * ux);
            float vy  = COV_NORM_ * (uyy - uy * uy);
            float vxy = COV_NORM_ * (uxy - ux * uy);
            float Sv = ((2.f * ux * uy + C1_) * (2.f * vxy + C2_)) /
                       ((ux * ux + uy * uy + C1_) * (vx + vy + C2_));
            acc += (double)Sv;
        }
        if (ok && fo + 1 <= 1021) {
            float ux  = wx1 * inv49, uy  = wy1 * inv49;
            float uxx = wxx1 * inv49, uyy = wyy1 * inv49, uxy = wxy1 * inv49;
            float vx  = COV_NORM_ * (uxx - ux * ux);
            float vy  = COV_NORM_ * (uyy - uy * uy);
            float vxy = COV_NORM_ * (uxy - ux * uy);
            float Sv = ((2.f * ux * uy + C1_) * (2.f * vxy + C2_)) /
                       ((ux * ux + uy * uy + C1_) * (vx + vy + C2_));
            acc += (double)Sv;
        }

        {   // subtract row t-3
            float2 xv = sld2(X + (size_t)(t - 3) * F_STRIDE);
            float2 yv = sld2(Y + (size_t)(t - 3) * F_STRIDE);
            sx0 -= xv.x; sx1 -= xv.y; sy0 -= yv.x; sy1 -= yv.y;
            sxx0 -= xv.x*xv.x; sxx1 -= xv.y*xv.y;
            syy0 -= yv.x*yv.x; syy1 -= yv.y*yv.y;
            sxy0 -= xv.x*yv.x; sxy1 -= xv.y*yv.y;
        }
    }

    #pragma unroll
    for (int off = 32; off > 0; off >>= 1) acc += __shfl_down(acc, off, 64);
    if (lane == 0) atomicAdd(&out[cg], (float)(acc / (395.0 * 1019.0)));
}

// ---------- persistent fused producer/consumer kernel (G==64 path) ----------
__global__ __launch_bounds__(256, 8) void fused_kernel(
    const float* __restrict__ x0, const float* __restrict__ x1,
    float* __restrict__ ws, float* __restrict__ out)
{
    __shared__ float2 buf[2 * NC];
    __shared__ int s_ticket;

    int* cnt = (int*)(ws + CNT_OFF);
    const int tid = threadIdx.x;
    const size_t perT = (size_t)T_FRAMES * F_STRIDE;
    int phase = 0;

    for (;;) {
        __syncthreads();                        // protect buf + s_ticket reuse
        if (tid == 0) {
            int tk;
            if (phase == 0) {
                tk = __hip_atomic_fetch_add(&cnt[0], 1, __ATOMIC_RELAXED, __HIP_MEMORY_SCOPE_AGENT);
                if (tk >= NTICK_STFT)
                    tk = NTICK_STFT + __hip_atomic_fetch_add(&cnt[65], 1, __ATOMIC_RELAXED, __HIP_MEMORY_SCOPE_AGENT);
            } else {
                tk = NTICK_STFT + __hip_atomic_fetch_add(&cnt[65], 1, __ATOMIC_RELAXED, __HIP_MEMORY_SCOPE_AGENT);
            }
            s_ticket = tk;
        }
        __syncthreads();
        const int ticket = s_ticket;
        if (ticket >= NTICK_STFT) phase = 1;

        if (ticket < NTICK_STFT) {
            const int ch = ticket / T_FRAMES;           // channel-major: channels finish early
            const int t  = ticket - ch * T_FRAMES;
            float* sout0 = ws + SPEC_OFF + (size_t)ch * perT + (size_t)t * F_STRIDE;
            float* sout1 = sout0 + (size_t)N_CH * perT;
            stft_pair_body<true>(x0 + (size_t)ch * S_LEN, x1 + (size_t)ch * S_LEN,
                                 ws, buf, t, sout0, sout1, tid);
            __syncthreads();                            // vmcnt(0): agent stores complete
            if (tid == 0)
                __hip_atomic_fetch_add(&cnt[1 + ch], 1, __ATOMIC_RELEASE, __HIP_MEMORY_SCOPE_AGENT);
        } else if (ticket < NTICK_STFT + NTICK_SSIM) {
            const int wid = (ticket - NTICK_STFT) * 4 + (tid >> 6);
            ssim_wave(ws, out, cnt, wid, tid & 63);
        } else {
            break;
        }
    }
}

// ---------- legacy fallback kernels (G < 64) ----------
__global__ __launch_bounds__(256, 8) void stft_mag_kernel(
    const float* __restrict__ x0, const float* __restrict__ x1,
    float* __restrict__ ws, int ch0, int nch, int swizzle)
{
    __shared__ float2 buf[2 * NC];
    const int tid = threadIdx.x;

    int ch, t;
    if (swizzle) {
        int g = blockIdx.x;
        ch = ch0 + (g & 7) * 8 + ((g >> 3) & 7);
        t  = g >> 6;
    } else {
        t  = blockIdx.x;
        ch = ch0 + blockIdx.y;
    }

    const size_t perT = (size_t)T_FRAMES * F_STRIDE;
    float* sout0 = ws + SPEC_OFF + (size_t)(ch - ch0) * perT + (size_t)t * F_STRIDE;
    float* sout1 = sout0 + (size_t)nch * perT;
    stft_pair_body<false>(x0 + (size_t)ch * S_LEN, x1 + (size_t)ch * S_LEN,
                          ws, buf, t, sout0, sout1, tid);
}

#define HWIN7(sarr, W) {                                                     \
    float p0 = sarr[0], p01 = p0 + sarr[1], p012 = p01 + sarr[2],            \
          P = p012 + sarr[3];                                                \
    float a1 = __shfl_down(p012, 1, 64);                                     \
    float A1 = __shfl_down(P,    1, 64);                                     \
    float b0 = __shfl_down(p0,   2, 64);                                     \
    float b1 = __shfl_down(p01,  2, 64);                                     \
    W[0] = P + a1;                                                           \
    W[1] = P - p0 + A1;                                                      \
    W[2] = W[1] - sarr[1] + b0;                                              \
    W[3] = W[2] - sarr[2] + (b1 - b0);                                       \
}

__global__ __launch_bounds__(256) void ssim_kernel(
    const float* __restrict__ ws, float* __restrict__ out,
    int ch0, int nch)
{
    const int tid  = threadIdx.x;
    const int wid  = blockIdx.x * 4 + (tid >> 6);
    const int lane = tid & 63;
    const int total = nch * BANDS * NCHUNKS_R;
    if (wid >= total) return;

    const int cg    = wid / (BANDS * NCHUNKS_R);
    const int rem   = wid - cg * (BANDS * NCHUNKS_R);
    const int band  = rem / NCHUNKS_R;
    const int chunk = rem - band * NCHUNKS_R;

    const int t0 = 3 + chunk * ROWS_PW;
    const int t1 = min(t0 + ROWS_PW, T_FRAMES - 3);

    const int cb = band * BAND_ADV;
    int c4 = cb + 4 * lane;
    if (c4 > 1024) c4 = 1024;

    const size_t perT = (size_t)T_FRAMES * F_STRIDE;
    const float* __restrict__ X = ws + SPEC_OFF + (size_t)cg * perT + c4;
    const float* __restrict__ Y = ws + SPEC_OFF + ((size_t)nch + cg) * perT + c4;

    const int  fo      = cb + 3 + 4 * lane;
    const bool lane_ok = (lane <= 61);
    const float inv49  = 1.0f / 49.0f;

    float sx[4] = {0,0,0,0}, sy[4] = {0,0,0,0}, sxx[4] = {0,0,0,0},
          syy[4] = {0,0,0,0}, sxy[4] = {0,0,0,0};

    for (int rr = t0 - 3; rr < t0 + 3; ++rr) {
        float4 xv = *(const float4*)(X + (size_t)rr * F_STRIDE);
        float4 yv = *(const float4*)(Y + (size_t)rr * F_STRIDE);
        float xa[4] = {xv.x, xv.y, xv.z, xv.w}, ya[4] = {yv.x, yv.y, yv.z, yv.w};
        #pragma unroll
        for (int c = 0; c < 4; ++c) {
            sx[c] += xa[c]; sy[c] += ya[c];
            sxx[c] += xa[c]*xa[c]; syy[c] += ya[c]*ya[c]; sxy[c] += xa[c]*ya[c];
        }
    }

    double acc = 0.0;

    #pragma unroll 1
    for (int t = t0; t < t1; ++t) {
        {
            float4 xv = *(const float4*)(X + (size_t)(t + 3) * F_STRIDE);
            float4 yv = *(const float4*)(Y + (size_t)(t + 3) * F_STRIDE);
            float xa[4] = {xv.x, xv.y, xv.z, xv.w}, ya[4] = {yv.x, yv.y, yv.z, yv.w};
            #pragma unroll
            for (int c = 0; c < 4; ++c) {
                sx[c] += xa[c]; sy[c] += ya[c];
                sxx[c] += xa[c]*xa[c]; syy[c] += ya[c]*ya[c]; sxy[c] += xa[c]*ya[c];
            }
        }

        float wx[4], wy[4], wxx[4], wyy[4], wxy[4];
        HWIN7(sx,  wx);
        HWIN7(sy,  wy);
        HWIN7(sxx, wxx);
        HWIN7(syy, wyy);
        HWIN7(sxy, wxy);

        #pragma unroll
        for (int c = 0; c < 4; ++c) {
            if (lane_ok && (fo + c <= 1021)) {
                float ux  = wx[c]  * inv49, uy  = wy[c]  * inv49;
                float uxx = wxx[c] * inv49, uyy = wyy[c] * inv49, uxy = wxy[c] * inv49;
                float vx  = COV_NORM_ * (uxx - ux * ux);
                float vy  = COV_NORM_ * (uyy - uy * uy);
                float vxy = COV_NORM_ * (uxy - ux * uy);
                float Sv = ((2.f * ux * uy + C1_) * (2.f * vxy + C2_)) /
                           ((ux * ux + uy * uy + C1_) * (vx + vy + C2_));
                acc += (double)Sv;
            }
        }

        {
            float4 xv = *(const float4*)(X + (size_t)(t - 3) * F_STRIDE);
            float4 yv = *(const float4*)(Y + (size_t)(t - 3) * F_STRIDE);
            float xa[4] = {xv.x, xv.y, xv.z, xv.w}, ya[4] = {yv.x, yv.y, yv.z, yv.w};
            #pragma unroll
            for (int c = 0; c < 4; ++c) {
                sx[c] -= xa[c]; sy[c] -= ya[c];
                sxx[c] -= xa[c]*xa[c]; syy[c] -= ya[c]*ya[c]; sxy[c] -= xa[c]*ya[c];
            }
        }
    }

    #pragma unroll
    for (int off = 32; off > 0; off >>= 1) acc += __shfl_down(acc, off, 64);
    if (lane == 0) {
        atomicAdd(&out[ch0 + cg], (float)(acc / (395.0 * 1019.0)));
    }
}

extern "C" void kernel_launch(void* const* d_in, const int* in_sizes, int n_in,
                              void* d_out, int out_size, void* d_ws, size_t ws_size,
                              hipStream_t stream) {
    const float* x0 = (const float*)d_in[0];   // output
    const float* x1 = (const float*)d_in[1];   // target
    float* out = (float*)d_out;
    float* ws  = (float*)d_ws;

    const size_t table_bytes  = (size_t)SPEC_OFF * sizeof(float);
    const size_t per_ch_bytes = (size_t)2 * T_FRAMES * F_STRIDE * sizeof(float);
    int G = (int)((ws_size - table_bytes) / per_ch_bytes);
    if (G > N_CH) G = N_CH;
    if (G < 1)    G = 1;

    init_tables_kernel<<<dim3(16), dim3(256), 0, stream>>>(ws, out);

    if (G >= N_CH) {
        // persistent fused producer/consumer: stft tickets then ssim tickets
        fused_kernel<<<dim3(PERSIST_BLOCKS), dim3(256), 0, stream>>>(x0, x1, ws, out);
    } else {
        for (int ch0 = 0; ch0 < N_CH; ch0 += G) {
            const int nch = (N_CH - ch0 < G) ? (N_CH - ch0) : G;
            stft_mag_kernel<<<dim3(T_FRAMES, nch), dim3(256), 0, stream>>>(x0, x1, ws, ch0, nch, 0);
            const int nwaves = nch * BANDS * NCHUNKS_R;
            ssim_kernel<<<dim3((nwaves + 3) / 4), dim3(256), 0, stream>>>(ws, out, ch0, nch);
        }
    }
}

// Round 7
// 351.250 us; speedup vs baseline: 6.4422x; 6.4422x over previous
//
#include <hip/hip_runtime.h>
#include <math.h>

#ifndef M_PI
#define M_PI 3.14159265358979323846
#endif

constexpr int S_LEN    = 176400;
constexpr int NFFT     = 2048;
constexpr int NC       = 1024;
constexpr int HOP_     = 441;
constexpr int T_FRAMES = 401;
constexpr int F_BINS   = 1025;
constexpr int F_STRIDE = 1028;     // fp32 spec row stride (16B aligned)
constexpr int N_CH     = 64;
constexpr float EPS_   = 1e-8f;
constexpr float C1_    = 0.0004f;
constexpr float C2_    = 0.0036f;
constexpr float COV_NORM_ = 49.0f / 48.0f;

// workspace float offsets
constexpr int WIN_OFF  = 0;        // float[2048] hann window
constexpr int TWG_OFF  = 2048;     // float2[768]  tw[e] = exp(-2pi i e/1024)
constexpr int UTW_OFF  = 3584;     // float2[1025] exp(-i pi r/1024)
constexpr int SPEC_OFF = 5696;

// ssim wave decomposition: 5 column bands x 17 row chunks per channel (R5)
constexpr int ROWS_PW   = 24;
constexpr int NCHUNKS_R = 17;      // ceil(395/24)
constexpr int BANDS     = 5;
constexpr int BAND_ADV  = 248;     // 62 producing lanes * 4 cols

// native 2xf32 vector type -> VGPR pair, usable as inline-asm operand
typedef float vf2 __attribute__((ext_vector_type(2)));

// LDS bank swizzle: phys(i) = i ^ ((i>>2)&15) ^ ((i>>6)&15) (bijective,
// conflict-checked per access pattern in R2).
__device__ __forceinline__ int phys(int i) { return i ^ ((i >> 2) & 15) ^ ((i >> 6) & 15); }

// ---- packed-f32 complex primitives (VOP3P).  R6 post-mortem: compiler
// scalarizes float2 math (VGPR=24, ~80 VALU/stage); these cut the radix-4
// butterfly from ~34 scalar to 14 packed VALU ops.  Register-only asm,
// non-volatile: scheduler may interleave freely.
__device__ __forceinline__ vf2 pk_add(vf2 a, vf2 b) {
    vf2 r; asm("v_pk_add_f32 %0, %1, %2" : "=v"(r) : "v"(a), "v"(b)); return r;
}
__device__ __forceinline__ vf2 pk_sub(vf2 a, vf2 b) {
    vf2 r; asm("v_pk_add_f32 %0, %1, %2 neg_lo:[0,1] neg_hi:[0,1]" : "=v"(r) : "v"(a), "v"(b)); return r;
}
// {b.x + d.y, b.y - d.x}  == b - i*d
__device__ __forceinline__ vf2 pk_sub_i(vf2 b, vf2 d) {
    vf2 r; asm("v_pk_add_f32 %0, %1, %2 op_sel:[0,1] op_sel_hi:[1,0] neg_hi:[0,1]"
               : "=v"(r) : "v"(b), "v"(d)); return r;
}
// {b.x - d.y, b.y + d.x}  == b + i*d
__device__ __forceinline__ vf2 pk_add_i(vf2 b, vf2 d) {
    vf2 r; asm("v_pk_add_f32 %0, %1, %2 op_sel:[0,1] op_sel_hi:[1,0] neg_lo:[0,1]"
               : "=v"(r) : "v"(b), "v"(d)); return r;
}
// complex multiply y*w: t = {y.x*w.x, y.x*w.y}; r = {t.lo - y.y*w.y, t.hi + y.y*w.x}
__device__ __forceinline__ vf2 pk_cmul(vf2 y, vf2 w) {
    vf2 t, r;
    asm("v_pk_mul_f32 %0, %1, %2 op_sel:[0,0] op_sel_hi:[0,1]"
        : "=v"(t) : "v"(y), "v"(w));
    asm("v_pk_fma_f32 %0, %1, %2, %3 op_sel:[1,1,0] op_sel_hi:[1,0,1] neg_lo:[1,0,0]"
        : "=v"(r) : "v"(y), "v"(w), "v"(t));
    return r;
}

__global__ __launch_bounds__(256) void init_tables_kernel(float* __restrict__ ws, float* __restrict__ out) {
    const int idx = blockIdx.x * 256 + threadIdx.x;
    if (idx < 64) out[idx] = 0.0f;
    if (idx < NFFT) {
        ws[WIN_OFF + idx] = 0.5f - 0.5f * cosf((float)(2.0 * M_PI / NFFT) * (float)idx);
    }
    if (idx < 768) {
        float ang = -2.0f * (float)M_PI * (float)idx / (float)NC;
        float s, c; sincosf(ang, &s, &c);
        ws[TWG_OFF + 2*idx] = c; ws[TWG_OFF + 2*idx+1] = s;
    }
    if (idx < F_BINS) {
        float ang = -(float)M_PI * (float)idx / (float)NC;
        float s, c; sincosf(ang, &s, &c);
        ws[UTW_OFF + 2*idx] = c; ws[UTW_OFF + 2*idx+1] = s;
    }
}

// In-place radix-4 DIF butterfly, packed-f32 (semantics identical to R2-R5):
//   a=x0+x2, b=x0-x2, c=x1+x3, d=x1-x3
//   y0=a+c, y1=(b-i*d)*w1, y2=(a-c)*w2, y3=(b+i*d)*w3
__device__ __forceinline__ void r4_dif_inplace(
    vf2* __restrict__ A, int r0, int r1, int r2, int r3,
    vf2 w1, vf2 w2, vf2 w3, bool tw)
{
    vf2 x0c = A[r0];
    vf2 x1c = A[r1];
    vf2 x2c = A[r2];
    vf2 x3c = A[r3];

    vf2 a = pk_add(x0c, x2c);
    vf2 b = pk_sub(x0c, x2c);
    vf2 c = pk_add(x1c, x3c);
    vf2 d = pk_sub(x1c, x3c);

    vf2 y0 = pk_add(a, c);
    vf2 y2 = pk_sub(a, c);
    vf2 y1 = pk_sub_i(b, d);
    vf2 y3 = pk_add_i(b, d);

    A[r0] = y0;
    A[r1] = tw ? pk_cmul(y1, w1) : y1;
    A[r2] = tw ? pk_cmul(y2, w2) : y2;
    A[r3] = tw ? pk_cmul(y3, w3) : y3;
}

// Dual 1024-pt in-place radix-4 DIF; one block = frame t of channel ch, both
// tensors.  16 KB LDS -> 8 blocks/CU.  chbase/nlay parameterize the spec
// layout so the G=64 path can split channels across dispatches while keeping
// one global layout (ssim reads [cg*perT] / [(nlay+cg)*perT]).
__global__ __launch_bounds__(256, 8) void stft_mag_kernel(
    const float* __restrict__ x0, const float* __restrict__ x1,
    float* __restrict__ ws, int ch0, int chbase, int nlay)
{
    __shared__ vf2 buf[2 * NC];   // FFT0 at [0,NC), FFT1 at [NC,2NC)

    const int tid = threadIdx.x;
    const int t   = blockIdx.x;
    const int ch  = ch0 + blockIdx.y;

    const float* __restrict__ xin0 = x0 + (size_t)ch * S_LEN;
    const float* __restrict__ xin1 = x1 + (size_t)ch * S_LEN;
    const float* __restrict__ win  = ws + WIN_OFF;
    const vf2*   __restrict__ twg  = (const vf2*)(ws + TWG_OFF);
    const vf2*   __restrict__ utw  = (const vf2*)(ws + UTW_OFF);

    // ---- pack: flat float index n over [0,2048); complex ci = n>>1 (swizzled)
    const int base = t * HOP_ - NFFT / 2;
    float* fA0 = (float*)buf;             // FFT0
    float* fA1 = (float*)(buf + NC);      // FFT1 (+8 KB)
    if (base >= 0 && base + NFFT <= S_LEN) {
        #pragma unroll
        for (int k = 0; k < NFFT / 256; ++k) {
            int n = k * 256 + tid;
            int j = base + n;
            float w = win[n];
            int p = 2 * phys(n >> 1) + (n & 1);
            fA0[p] = xin0[j] * w;
            fA1[p] = xin1[j] * w;
        }
    } else {
        #pragma unroll
        for (int k = 0; k < NFFT / 256; ++k) {
            int n = k * 256 + tid;
            int j = base + n;
            j = (j < 0) ? -j : j;
            j = (j >= S_LEN) ? (2 * S_LEN - 2 - j) : j;
            float w = win[n];
            int p = 2 * phys(n >> 1) + (n & 1);
            fA0[p] = xin0[j] * w;
            fA1[p] = xin1[j] * w;
        }
    }
    __syncthreads();

    // ---- 5-stage in-place radix-4 DIF, x2 FFTs
    #pragma unroll
    for (int s = 0; s < 5; ++s) {
        const int M  = 256 >> (2 * s);
        const int q  = tid & (M - 1);
        const int e  = q << (2 * s);
        const int i0 = 4 * (tid - q) + q;

        const int r0 = phys(i0);
        const int r1 = phys(i0 + M);
        const int r2 = phys(i0 + 2 * M);
        const int r3 = phys(i0 + 3 * M);

        vf2 w1, w2, w3;
        if (s < 4) {
            w1 = twg[e];
            w2 = twg[2 * e];
            w3 = twg[3 * e];
        } else {
            w1.x = 1.0f; w1.y = 0.0f; w2 = w1; w3 = w1;
        }

        r4_dif_inplace(buf,      r0, r1, r2, r3, w1, w2, w3, s < 4);
        r4_dif_inplace(buf + NC, r0, r1, r2, r3, w1, w2, w3, s < 4);

        __syncthreads();
    }

    // ---- real-FFT unpack + magnitude + fp32 coalesced stores (both tensors)
    const size_t perT = (size_t)T_FRAMES * F_STRIDE;
    float* __restrict__ sout0 =
        ws + SPEC_OFF + (size_t)(ch - chbase) * perT + (size_t)t * F_STRIDE;
    float* __restrict__ sout1 = sout0 + (size_t)nlay * perT;

    const int R8 = ((tid & 3) << 6) | ((tid & 12) << 2) | ((tid >> 2) & 12) | ((tid >> 6) & 3);

    #pragma unroll
    for (int k = 0; k < 5; ++k) {
        int r = k * 256 + tid;
        if (k < 4 || tid == 0) {
            const int ra = (k < 4) ? ((R8 << 2) | k) : 0;          // rev4(r & 1023)
            const int rn = (NC - r) & (NC - 1);
            const int rb = ((rn & 3) << 8) | ((rn & 12) << 4) | (rn & 48)
                         | ((rn >> 4) & 12) | ((rn >> 8) & 3);     // rev4(rn)
            const int ia = phys(ra);
            const int ib = phys(rb);
            vf2 wu = utw[r];

            {   // tensor 0
                vf2 Zr = buf[ia];
                vf2 Zn = buf[ib];
                float Ex = 0.5f * (Zr.x + Zn.x);
                float Ey = 0.5f * (Zr.y - Zn.y);
                float Ox = 0.5f * (Zr.y + Zn.y);
                float Oy = 0.5f * (Zn.x - Zr.x);
                float Xx = Ex + wu.x * Ox - wu.y * Oy;
                float Xy = Ey + wu.x * Oy + wu.y * Ox;
                sout0[r] = sqrtf(fmaxf(Xx * Xx + Xy * Xy, EPS_));
            }
            {   // tensor 1
                vf2 Zr = buf[NC + ia];
                vf2 Zn = buf[NC + ib];
                float Ex = 0.5f * (Zr.x + Zn.x);
                float Ey = 0.5f * (Zr.y - Zn.y);
                float Ox = 0.5f * (Zr.y + Zn.y);
                float Oy = 0.5f * (Zn.x - Zr.x);
                float Xx = Ex + wu.x * Ox - wu.y * Oy;
                float Xy = Ey + wu.x * Oy + wu.y * Ox;
                sout1[r] = sqrtf(fmaxf(Xx * Xx + Xy * Xy, EPS_));
            }
        }
    }
}

// SSIM v3 (bit-identical to R5 -- kept fixed this round so the newly-surfaced
// rocprof counters attribute cleanly): read-once 6-row register ring, wave per
// (channel, band, 24-row chunk), horizontal 7-window via lane prefixes +
// __shfl_down, one-ahead prefetch.
#define HWIN7(sarr, W) {                                                     \
    float p0 = sarr[0], p01 = p0 + sarr[1], p012 = p01 + sarr[2],            \
          P = p012 + sarr[3];                                                \
    float a1 = __shfl_down(p012, 1, 64);                                     \
    float A1 = __shfl_down(P,    1, 64);                                     \
    float b0 = __shfl_down(p0,   2, 64);                                     \
    float b1 = __shfl_down(p01,  2, 64);                                     \
    W[0] = P + a1;                                                           \
    W[1] = P - p0 + A1;                                                      \
    W[2] = W[1] - sarr[1] + b0;                                              \
    W[3] = W[2] - sarr[2] + (b1 - b0);                                       \
}

__global__ __launch_bounds__(256) void ssim_kernel(
    const float* __restrict__ ws, float* __restrict__ out,
    int ch0, int nch)
{
    const int tid  = threadIdx.x;
    const int wid  = blockIdx.x * 4 + (tid >> 6);
    const int lane = tid & 63;
    const int total = nch * BANDS * NCHUNKS_R;
    if (wid >= total) return;

    const int cg    = wid / (BANDS * NCHUNKS_R);
    const int rem   = wid - cg * (BANDS * NCHUNKS_R);
    const int band  = rem / NCHUNKS_R;
    const int chunk = rem - band * NCHUNKS_R;

    const int t0 = 3 + chunk * ROWS_PW;
    const int t1 = min(t0 + ROWS_PW, T_FRAMES - 3);   // <= 398

    const int cb = band * BAND_ADV;
    int c4 = cb + 4 * lane;
    if (c4 > 1024) c4 = 1024;      // stay inside the 1028-float row (no OOB)

    const size_t perT = (size_t)T_FRAMES * F_STRIDE;
    const float* __restrict__ X = ws + SPEC_OFF + (size_t)cg * perT + c4;
    const float* __restrict__ Y = ws + SPEC_OFF + ((size_t)nch + cg) * perT + c4;

    const int  fo      = cb + 3 + 4 * lane;   // first output col of this lane
    const bool lane_ok = (lane <= 61);
    const float inv49  = 1.0f / 49.0f;

    float sx[4] = {0,0,0,0}, sy[4] = {0,0,0,0}, sxx[4] = {0,0,0,0},
          syy[4] = {0,0,0,0}, sxy[4] = {0,0,0,0};
    float rgx[6][4], rgy[6][4];    // ring of raw (x,y) rows t-3..t+2

    #pragma unroll
    for (int w = 0; w < 6; ++w) {
        const int rr = t0 - 3 + w;
        float4 xv = *(const float4*)(X + (size_t)rr * F_STRIDE);
        float4 yv = *(const float4*)(Y + (size_t)rr * F_STRIDE);
        float xa[4] = {xv.x, xv.y, xv.z, xv.w}, ya[4] = {yv.x, yv.y, yv.z, yv.w};
        #pragma unroll
        for (int c = 0; c < 4; ++c) {
            sx[c] += xa[c]; sy[c] += ya[c];
            sxx[c] += xa[c]*xa[c]; syy[c] += ya[c]*ya[c]; sxy[c] += xa[c]*ya[c];
            rgx[w][c] = xa[c]; rgy[w][c] = ya[c];
        }
    }

    float4 cxa = *(const float4*)(X + (size_t)(t0 + 3) * F_STRIDE);
    float4 cya = *(const float4*)(Y + (size_t)(t0 + 3) * F_STRIDE);

    double acc = 0.0;

    #pragma unroll 1
    for (int tb = t0; tb < t1; tb += 6) {
        #pragma unroll
        for (int j = 0; j < 6; ++j) {
            const int t = tb + j;
            const int tn = min(t + 4, T_FRAMES - 1);
            float4 nxa = *(const float4*)(X + (size_t)tn * F_STRIDE);
            float4 nya = *(const float4*)(Y + (size_t)tn * F_STRIDE);

            float xa[4] = {cxa.x, cxa.y, cxa.z, cxa.w};
            float ya[4] = {cya.x, cya.y, cya.z, cya.w};

            #pragma unroll
            for (int c = 0; c < 4; ++c) {
                sx[c] += xa[c]; sy[c] += ya[c];
                sxx[c] += xa[c]*xa[c]; syy[c] += ya[c]*ya[c]; sxy[c] += xa[c]*ya[c];
            }

            float wx[4], wy[4], wxx[4], wyy[4], wxy[4];
            HWIN7(sx,  wx);
            HWIN7(sy,  wy);
            HWIN7(sxx, wxx);
            HWIN7(syy, wyy);
            HWIN7(sxy, wxy);

            const bool live = (t < t1);
            #pragma unroll
            for (int c = 0; c < 4; ++c) {
                if (live && lane_ok && (fo + c <= 1021)) {
                    float ux  = wx[c]  * inv49, uy  = wy[c]  * inv49;
                    float uxx = wxx[c] * inv49, uyy = wyy[c] * inv49, uxy = wxy[c] * inv49;
                    float vx  = COV_NORM_ * (uxx - ux * ux);
                    float vy  = COV_NORM_ * (uyy - uy * uy);
                    float vxy = COV_NORM_ * (uxy - ux * uy);
                    float Sv = ((2.f * ux * uy + C1_) * (2.f * vxy + C2_)) /
                               ((ux * ux + uy * uy + C1_) * (vx + vy + C2_));
                    acc += (double)Sv;
                }
            }

            #pragma unroll
            for (int c = 0; c < 4; ++c) {
                float bx_ = rgx[j][c], by_ = rgy[j][c];
                sx[c]  -= bx_;      sy[c]  -= by_;
                sxx[c] -= bx_*bx_;  syy[c] -= by_*by_;  sxy[c] -= bx_*by_;
                rgx[j][c] = xa[c];  rgy[j][c] = ya[c];
            }

            cxa = nxa; cya = nya;
        }
    }

    #pragma unroll
    for (int off = 32; off > 0; off >>= 1) acc += __shfl_down(acc, off, 64);
    if (lane == 0) {
        atomicAdd(&out[ch0 + cg], (float)(acc / (395.0 * 1019.0)));
    }
}

extern "C" void kernel_launch(void* const* d_in, const int* in_sizes, int n_in,
                              void* d_out, int out_size, void* d_ws, size_t ws_size,
                              hipStream_t stream) {
    const float* x0 = (const float*)d_in[0];   // output
    const float* x1 = (const float*)d_in[1];   // target
    float* out = (float*)d_out;
    float* ws  = (float*)d_ws;

    const size_t table_bytes  = (size_t)SPEC_OFF * sizeof(float);
    const size_t per_ch_bytes = (size_t)2 * T_FRAMES * F_STRIDE * sizeof(float);
    int G = (int)((ws_size - table_bytes) / per_ch_bytes);
    if (G > N_CH) G = N_CH;
    if (G < 1)    G = 1;

    init_tables_kernel<<<dim3(16), dim3(256), 0, stream>>>(ws, out);

    if (G >= N_CH) {
        // stft split into two 32-channel dispatches (same total work) so the
        // ssim dispatch becomes the longest one and surfaces in rocprof top-5.
        stft_mag_kernel<<<dim3(T_FRAMES, 32), dim3(256), 0, stream>>>(x0, x1, ws,  0, 0, N_CH);
        stft_mag_kernel<<<dim3(T_FRAMES, 32), dim3(256), 0, stream>>>(x0, x1, ws, 32, 0, N_CH);
        const int nwaves = N_CH * BANDS * NCHUNKS_R;
        ssim_kernel<<<dim3((nwaves + 3) / 4), dim3(256), 0, stream>>>(ws, out, 0, N_CH);
    } else {
        for (int ch0 = 0; ch0 < N_CH; ch0 += G) {
            const int nch = (N_CH - ch0 < G) ? (N_CH - ch0) : G;
            stft_mag_kernel<<<dim3(T_FRAMES, nch), dim3(256), 0, stream>>>(x0, x1, ws, ch0, ch0, nch);
            const int nwaves = nch * BANDS * NCHUNKS_R;
            ssim_kernel<<<dim3((nwaves + 3) / 4), dim3(256), 0, stream>>>(ws, out, ch0, nch);
        }
    }
}